// Round 8
// baseline (1258.048 us; speedup 1.0000x reference)
//
#include <hip/hip_runtime.h>
#include <hip/hip_bf16.h>

#define D 64
#define THREADS 256
#define BKT_BITS 9                 // 512 nodes per bucket
#define BKT_NODES (1 << BKT_BITS)
#define CHUNK 8192                 // edges per pass-1 block
#define ROWPAD 8                   // rows padded to multiple of 8 edges
#define PADMAX (BKT_NODES * (ROWPAD - 1))   // max pad per bucket

// ---- bf16 helpers (bit tricks, RNE) ----
__device__ __forceinline__ unsigned f2bf(float f) {
    unsigned u = __float_as_uint(f);
    return (u + 0x7fffu + ((u >> 16) & 1u)) >> 16;
}
__device__ __forceinline__ float2 bfpair(unsigned v) {
    return make_float2(__uint_as_float(v << 16), __uint_as_float(v & 0xffff0000u));
}

// ---- p1a: per-chunk LDS histogram of coarse buckets (B <= 256) ----
__global__ void p1a_hist(const int* __restrict__ dst, int* __restrict__ blockCount,
                         int E, int B) {
    __shared__ int lc[256];
    int t = threadIdx.x;
    lc[t] = 0;
    __syncthreads();
    int base = blockIdx.x * CHUNK;
    int end = min(base + CHUNK, E);
    for (int e = base + t; e < end; e += THREADS)
        atomicAdd(&lc[dst[e] >> BKT_BITS], 1);
    __syncthreads();
    if (t < B) blockCount[(long long)blockIdx.x * B + t] = lc[t];
}

// ---- p1b: per-bucket exclusive scan over blocks (in place) + bucket totals ----
__global__ void p1b_scanblocks(int* __restrict__ blockCount, int* __restrict__ total,
                               int NBLK, int B) {
    __shared__ int sm[256];
    int b = blockIdx.x, t = threadIdx.x;
    int run = 0;
    for (int base = 0; base < NBLK; base += 256) {
        int i = base + t;
        int v = (i < NBLK) ? blockCount[(long long)i * B + b] : 0;
        sm[t] = v;
        __syncthreads();
        for (int off = 1; off < 256; off <<= 1) {
            int u = (t >= off) ? sm[t - off] : 0;
            __syncthreads();
            sm[t] += u;
            __syncthreads();
        }
        if (i < NBLK) blockCount[(long long)i * B + b] = run + sm[t] - v;
        run += sm[255];
        __syncthreads();
    }
    if (t == 0) total[b] = run;
}

// ---- p1c: exclusive scan of bucket totals -> bstart[B+1] ----
__global__ void p1c_scanbuckets(const int* __restrict__ total, int* __restrict__ bstart,
                                int B, int E) {
    __shared__ int sm[256];
    int t = threadIdx.x;
    int run = 0;
    for (int base = 0; base < B; base += 256) {
        int i = base + t;
        int v = (i < B) ? total[i] : 0;
        sm[t] = v;
        __syncthreads();
        for (int off = 1; off < 256; off <<= 1) {
            int u = (t >= off) ? sm[t - off] : 0;
            __syncthreads();
            sm[t] += u;
            __syncthreads();
        }
        if (i < B) bstart[i] = run + sm[t] - v;
        run += sm[255];
        __syncthreads();
    }
    if (t == 0) bstart[B] = E;
}

// ---- p1d: scatter edges into bucket-partitioned temp via LDS cursors ----
// temp[pos] = (src | dstlow<<17, w)   [src < 2^17 since N=100k]
__global__ void p1d_scatter(const int* __restrict__ dst, const int* __restrict__ src,
                            const float* __restrict__ w, const int* __restrict__ blockCount,
                            const int* __restrict__ bstart, int2* __restrict__ temp,
                            int E, int B) {
    __shared__ int cur[256];
    int t = threadIdx.x;
    if (t < B) cur[t] = bstart[t] + blockCount[(long long)blockIdx.x * B + t];
    __syncthreads();
    int base = blockIdx.x * CHUNK;
    int end = min(base + CHUNK, E);
    for (int e = base + t; e < end; e += THREADS) {
        int d = dst[e];
        int b = d >> BKT_BITS;
        int pos = atomicAdd(&cur[b], 1);                       // LDS atomic w/ return
        temp[pos] = make_int2(src[e] | ((d & (BKT_NODES - 1)) << 17),
                              __float_as_int(w[e]));
    }
}

// ---- p2a: per-bucket histogram + weighted degree -> norm + PADDED rowptr ----
// rows padded to multiple of ROWPAD; bucket base = roundup(bstart[b]) + PADMAX*b
__global__ void p2a_norm(const int2* __restrict__ temp, const int* __restrict__ bstart,
                         int* __restrict__ rowptrP, float* __restrict__ norm,
                         int N, int E, int B) {
    __shared__ int cnt[BKT_NODES];
    __shared__ float degs[BKT_NODES];
    __shared__ int sm[256];
    __shared__ int rowst[BKT_NODES];
    int b = blockIdx.x, t = threadIdx.x;
    int ebeg = bstart[b], eend = bstart[b + 1];
    for (int i = t; i < BKT_NODES; i += THREADS) { cnt[i] = 0; degs[i] = 0.0f; }
    __syncthreads();
    for (int e = ebeg + t; e < eend; e += THREADS) {
        int2 pk = temp[e];
        int dl = (pk.x >> 17) & (BKT_NODES - 1);
        atomicAdd(&cnt[dl], 1);
        atomicAdd(&degs[dl], __int_as_float(pk.y));
    }
    __syncthreads();
    // exclusive scan of padded counts
    int run = 0;
    for (int base = 0; base < BKT_NODES; base += 256) {
        int v = (cnt[base + t] + (ROWPAD - 1)) & ~(ROWPAD - 1);
        sm[t] = v;
        __syncthreads();
        for (int off = 1; off < 256; off <<= 1) {
            int u = (t >= off) ? sm[t - off] : 0;
            __syncthreads();
            sm[t] += u;
            __syncthreads();
        }
        rowst[base + t] = run + sm[t] - v;
        run += sm[255];
        __syncthreads();
    }
    int pbase = ((ebeg + (ROWPAD - 1)) & ~(ROWPAD - 1)) + PADMAX * b;
    int node0 = b << BKT_BITS;
    for (int i = t; i < BKT_NODES; i += THREADS) {
        rowptrP[node0 + i] = pbase + rowst[i];
        int node = node0 + i;
        if (node < N) norm[node] = rsqrtf(fmaxf(degs[i], 1.0f));
    }
    if (b == B - 1 && t == 0)
        rowptrP[(long long)B << BKT_BITS] = ((E + (ROWPAD - 1)) & ~(ROWPAD - 1)) + PADMAX * B;
}

// ---- p2b: placement with coef = w * norm[src] baked in; dummy-pad row tails ----
__global__ void p2b_place(const int2* __restrict__ temp, const int* __restrict__ bstart,
                          const int* __restrict__ rowptrP, const float* __restrict__ norm,
                          int2* __restrict__ packed, int N, int B) {
    __shared__ int cur[BKT_NODES];
    int b = blockIdx.x, t = threadIdx.x;
    int ebeg = bstart[b], eend = bstart[b + 1];
    int node0 = b << BKT_BITS;
    for (int i = t; i < BKT_NODES; i += THREADS) cur[i] = rowptrP[node0 + i];
    __syncthreads();
    for (int e = ebeg + t; e < eend; e += THREADS) {
        int2 pk = temp[e];
        int dl = (pk.x >> 17) & (BKT_NODES - 1);
        int s = pk.x & 0x1ffff;
        int pos = atomicAdd(&cur[dl], 1);                      // LDS atomic w/ return
        float c = __int_as_float(pk.y) * norm[s];
        packed[pos] = make_int2(s, __float_as_int(c));
    }
    __syncthreads();
    // pad tails of REAL rows with (src=0, coef=0) up to next row start
    for (int i = t; i < BKT_NODES; i += THREADS) {
        int node = node0 + i;
        if (node >= N) continue;
        int tail = cur[i];
        int next = rowptrP[node0 + i + 1];
        for (int p = tail; p < next; ++p) packed[p] = make_int2(0, 0);
    }
}

// ---- h (fp32) -> bf16 packed pairs, 4 elems/thread ----
__global__ void tobf16_kernel(const float* __restrict__ h, unsigned* __restrict__ hbf2,
                              long long nd4) {
    long long i = (long long)blockIdx.x * blockDim.x + threadIdx.x;
    if (i < nd4) {
        float4 v = ((const float4*)h)[i];
        ((uint2*)hbf2)[i] = make_uint2(f2bf(v.x) | (f2bf(v.y) << 16),
                                       f2bf(v.z) | (f2bf(v.w) << 16));
    }
}

// ======== gather core: 16 lanes/node, uint2 rows, 8-edge unroll, 8-deep MLP ========
// acc[4][4]: 4 banks x 4 dims; edge slots s and s+4 share bank s.
#define GATHER_LOOP(SRC_ARR)                                                        \
    float a0x = 0, a0y = 0, a0z = 0, a0w = 0;                                       \
    float a1x = 0, a1y = 0, a1z = 0, a1w = 0;                                       \
    float a2x = 0, a2y = 0, a2z = 0, a2w = 0;                                       \
    float a3x = 0, a3y = 0, a3z = 0, a3w = 0;                                       \
    for (; j < end; j += 8) {                                                       \
        int4 q0 = *(const int4*)(packed + j);                                       \
        int4 q1 = *(const int4*)(packed + j + 2);                                   \
        int4 q2 = *(const int4*)(packed + j + 4);                                   \
        int4 q3 = *(const int4*)(packed + j + 6);                                   \
        uint2 r0 = SRC_ARR[((long long)q0.x << 4) + lane];                          \
        uint2 r1 = SRC_ARR[((long long)q0.z << 4) + lane];                          \
        uint2 r2 = SRC_ARR[((long long)q1.x << 4) + lane];                          \
        uint2 r3 = SRC_ARR[((long long)q1.z << 4) + lane];                          \
        uint2 r4 = SRC_ARR[((long long)q2.x << 4) + lane];                          \
        uint2 r5 = SRC_ARR[((long long)q2.z << 4) + lane];                          \
        uint2 r6 = SRC_ARR[((long long)q3.x << 4) + lane];                          \
        uint2 r7 = SRC_ARR[((long long)q3.z << 4) + lane];                          \
        float c0 = __int_as_float(q0.y), c1 = __int_as_float(q0.w);                 \
        float c2 = __int_as_float(q1.y), c3 = __int_as_float(q1.w);                 \
        float c4 = __int_as_float(q2.y), c5 = __int_as_float(q2.w);                 \
        float c6 = __int_as_float(q3.y), c7 = __int_as_float(q3.w);                 \
        float2 f;                                                                   \
        f = bfpair(r0.x); a0x = fmaf(f.x, c0, a0x); a0y = fmaf(f.y, c0, a0y);       \
        f = bfpair(r0.y); a0z = fmaf(f.x, c0, a0z); a0w = fmaf(f.y, c0, a0w);       \
        f = bfpair(r1.x); a1x = fmaf(f.x, c1, a1x); a1y = fmaf(f.y, c1, a1y);       \
        f = bfpair(r1.y); a1z = fmaf(f.x, c1, a1z); a1w = fmaf(f.y, c1, a1w);       \
        f = bfpair(r2.x); a2x = fmaf(f.x, c2, a2x); a2y = fmaf(f.y, c2, a2y);       \
        f = bfpair(r2.y); a2z = fmaf(f.x, c2, a2z); a2w = fmaf(f.y, c2, a2w);       \
        f = bfpair(r3.x); a3x = fmaf(f.x, c3, a3x); a3y = fmaf(f.y, c3, a3y);       \
        f = bfpair(r3.y); a3z = fmaf(f.x, c3, a3z); a3w = fmaf(f.y, c3, a3w);       \
        f = bfpair(r4.x); a0x = fmaf(f.x, c4, a0x); a0y = fmaf(f.y, c4, a0y);       \
        f = bfpair(r4.y); a0z = fmaf(f.x, c4, a0z); a0w = fmaf(f.y, c4, a0w);       \
        f = bfpair(r5.x); a1x = fmaf(f.x, c5, a1x); a1y = fmaf(f.y, c5, a1y);       \
        f = bfpair(r5.y); a1z = fmaf(f.x, c5, a1z); a1w = fmaf(f.y, c5, a1w);       \
        f = bfpair(r6.x); a2x = fmaf(f.x, c6, a2x); a2y = fmaf(f.y, c6, a2y);       \
        f = bfpair(r6.y); a2z = fmaf(f.x, c6, a2z); a2w = fmaf(f.y, c6, a2w);       \
        f = bfpair(r7.x); a3x = fmaf(f.x, c7, a3x); a3y = fmaf(f.y, c7, a3y);       \
        f = bfpair(r7.y); a3z = fmaf(f.x, c7, a3z); a3w = fmaf(f.y, c7, a3w);       \
    }                                                                               \
    float s0 = (a0x + a1x) + (a2x + a3x);                                           \
    float s1 = (a0y + a1y) + (a2y + a3y);                                           \
    float s2 = (a0z + a1z) + (a2z + a3z);                                           \
    float s3 = (a0w + a1w) + (a2w + a3w);

// ---- gather layer 1: h1bf[i] = bf16( norm[i] * sum h0bf[src]*coef ) ----
__global__ __launch_bounds__(256, 4)
void gather1_kernel(const uint2* __restrict__ h_in, const int2* __restrict__ packed,
                    const int* __restrict__ rowptr, const float* __restrict__ norm,
                    uint2* __restrict__ h_out, int N) {
    int node = blockIdx.x * (blockDim.x >> 4) + (threadIdx.x >> 4);
    int lane = threadIdx.x & 15;
    if (node >= N) return;
    int j = rowptr[node], end = rowptr[node + 1];
    GATHER_LOOP(h_in)
    float nv = norm[node];
    s0 *= nv; s1 *= nv; s2 *= nv; s3 *= nv;
    h_out[((long long)node << 4) + lane] =
        make_uint2(f2bf(s0) | (f2bf(s1) << 16), f2bf(s2) | (f2bf(s3) << 16));
}

// ---- gather layer 2 + mean: out = (h0 + h1 + norm*sum h1[src]*coef)/3 ----
__global__ __launch_bounds__(256, 4)
void gather2_final_kernel(const uint2* __restrict__ h0bf, const uint2* __restrict__ h1bf,
                          const int2* __restrict__ packed, const int* __restrict__ rowptr,
                          const float* __restrict__ norm, float* __restrict__ out, int N) {
    int node = blockIdx.x * (blockDim.x >> 4) + (threadIdx.x >> 4);
    int lane = threadIdx.x & 15;
    if (node >= N) return;
    int j = rowptr[node], end = rowptr[node + 1];
    GATHER_LOOP(h1bf)
    long long idx = ((long long)node << 4) + lane;
    float nv = norm[node];
    uint2 h0r = h0bf[idx], h1r = h1bf[idx];
    float2 h0a = bfpair(h0r.x), h0b = bfpair(h0r.y);
    float2 h1a = bfpair(h1r.x), h1b = bfpair(h1r.y);
    float4 o;
    o.x = (h0a.x + h1a.x + s0 * nv) * (1.0f / 3.0f);
    o.y = (h0a.y + h1a.y + s1 * nv) * (1.0f / 3.0f);
    o.z = (h0b.x + h1b.x + s2 * nv) * (1.0f / 3.0f);
    o.w = (h0b.y + h1b.y + s3 * nv) * (1.0f / 3.0f);
    ((float4*)out)[idx] = o;
}

extern "C" void kernel_launch(void* const* d_in, const int* in_sizes, int n_in,
                              void* d_out, int out_size, void* d_ws, size_t ws_size,
                              hipStream_t stream) {
    const float* h   = (const float*)d_in[0];
    const float* w   = (const float*)d_in[1];
    const int*   src = (const int*)d_in[2];
    const int*   dst = (const int*)d_in[3];
    const int N = in_sizes[0] / D;   // 100000
    const int E = in_sizes[1];       // 1600000
    float* out = (float*)d_out;

    const int B = (N + BKT_NODES - 1) >> BKT_BITS;   // 196
    const int NBLK = (E + CHUNK - 1) / CHUNK;        // 196
    const int EPAD = ((E + (ROWPAD - 1)) & ~(ROWPAD - 1)) + PADMAX * B;

    // ---- workspace layout ----
    char* ws = (char*)d_ws;
    size_t off = 0;
    auto alloc = [&](size_t bytes, size_t align) -> char* {
        off = (off + align - 1) & ~(align - 1);
        char* p = ws + off;
        off += bytes;
        return p;
    };
    float* norm     = (float*)alloc((size_t)N * 4, 16);
    int*   rowptrP  = (int*)  alloc(((size_t)B * BKT_NODES + 1) * 4, 16);
    int*   total    = (int*)  alloc((size_t)B * 4, 16);
    int*   bstart   = (int*)  alloc((size_t)(B + 1) * 4, 16);
    int*   blockCnt = (int*)  alloc((size_t)NBLK * B * 4, 16);
    int2*  packed   = (int2*) alloc((size_t)EPAD * 8, 16);
    // temp (build phase) time-shares with h1bf (gather phase)
    char*  shared_region = alloc((size_t)E * 8, 128);
    int2*     temp = (int2*)shared_region;
    unsigned* h1bf = (unsigned*)shared_region;
    unsigned* h0bf = (unsigned*)alloc((size_t)N * D * 2, 128);

    const int nodes_per_block = THREADS / 16;        // 16 lanes per node
    const int gather_blocks = (N + nodes_per_block - 1) / nodes_per_block;
    const long long nd4 = (long long)N * D / 4;
    const int cvt_blocks = (int)((nd4 + THREADS - 1) / THREADS);

    // CSR build: zero global atomics, rows padded to multiple of 8, coef baked in
    p1a_hist<<<NBLK, THREADS, 0, stream>>>(dst, blockCnt, E, B);
    p1b_scanblocks<<<B, 256, 0, stream>>>(blockCnt, total, NBLK, B);
    p1c_scanbuckets<<<1, 256, 0, stream>>>(total, bstart, B, E);
    p1d_scatter<<<NBLK, THREADS, 0, stream>>>(dst, src, w, blockCnt, bstart, temp, E, B);
    p2a_norm<<<B, 256, 0, stream>>>(temp, bstart, rowptrP, norm, N, E, B);
    p2b_place<<<B, 256, 0, stream>>>(temp, bstart, rowptrP, norm, packed, N, B);

    // h -> bf16
    tobf16_kernel<<<cvt_blocks, THREADS, 0, stream>>>(h, h0bf, nd4);

    // gathers: 16 lanes/node, uint2 rows, 8-deep MLP, __launch_bounds__(256,4)
    gather1_kernel<<<gather_blocks, THREADS, 0, stream>>>((const uint2*)h0bf, packed, rowptrP,
                                                          norm, (uint2*)h1bf, N);
    gather2_final_kernel<<<gather_blocks, THREADS, 0, stream>>>((const uint2*)h0bf, (const uint2*)h1bf,
                                                                packed, rowptrP, norm, out, N);
}

// Round 9
// 234.818 us; speedup vs baseline: 5.3575x; 5.3575x over previous
//
#include <hip/hip_runtime.h>
#include <hip/hip_bf16.h>

#define D 64
#define THREADS 256
#define BKT_BITS 9                 // 512 nodes per bucket
#define BKT_NODES (1 << BKT_BITS)
#define CHUNK 8192                 // edges per pass-1 block

// ---- bf16 helpers (bit tricks, RNE) ----
__device__ __forceinline__ unsigned f2bf(float f) {
    unsigned u = __float_as_uint(f);
    return (u + 0x7fffu + ((u >> 16) & 1u)) >> 16;
}
__device__ __forceinline__ float2 bfpair(unsigned v) {
    return make_float2(__uint_as_float(v << 16), __uint_as_float(v & 0xffff0000u));
}

// ---- p1a: per-chunk LDS histogram of coarse buckets (B <= 256) ----
__global__ void p1a_hist(const int* __restrict__ dst, int* __restrict__ blockCount,
                         int E, int B) {
    __shared__ int lc[256];
    int t = threadIdx.x;
    lc[t] = 0;
    __syncthreads();
    int base = blockIdx.x * CHUNK;
    int end = min(base + CHUNK, E);
    for (int e = base + t; e < end; e += THREADS)
        atomicAdd(&lc[dst[e] >> BKT_BITS], 1);
    __syncthreads();
    if (t < B) blockCount[(long long)blockIdx.x * B + t] = lc[t];
}

// ---- p1b: per-bucket exclusive scan over blocks (in place) + bucket totals ----
__global__ void p1b_scanblocks(int* __restrict__ blockCount, int* __restrict__ total,
                               int NBLK, int B) {
    __shared__ int sm[256];
    int b = blockIdx.x, t = threadIdx.x;
    int run = 0;
    for (int base = 0; base < NBLK; base += 256) {
        int i = base + t;
        int v = (i < NBLK) ? blockCount[(long long)i * B + b] : 0;
        sm[t] = v;
        __syncthreads();
        for (int off = 1; off < 256; off <<= 1) {
            int u = (t >= off) ? sm[t - off] : 0;
            __syncthreads();
            sm[t] += u;
            __syncthreads();
        }
        if (i < NBLK) blockCount[(long long)i * B + b] = run + sm[t] - v;
        run += sm[255];
        __syncthreads();
    }
    if (t == 0) total[b] = run;
}

// ---- p1c: exclusive scan of bucket totals -> bstart[B+1] ----
__global__ void p1c_scanbuckets(const int* __restrict__ total, int* __restrict__ bstart,
                                int B, int E) {
    __shared__ int sm[256];
    int t = threadIdx.x;
    int run = 0;
    for (int base = 0; base < B; base += 256) {
        int i = base + t;
        int v = (i < B) ? total[i] : 0;
        sm[t] = v;
        __syncthreads();
        for (int off = 1; off < 256; off <<= 1) {
            int u = (t >= off) ? sm[t - off] : 0;
            __syncthreads();
            sm[t] += u;
            __syncthreads();
        }
        if (i < B) bstart[i] = run + sm[t] - v;
        run += sm[255];
        __syncthreads();
    }
    if (t == 0) bstart[B] = E;
}

// ---- p1d: scatter edges into bucket-partitioned temp via LDS cursors ----
// temp[pos] = (src | dstlow<<17, w)   [src < 2^17 since N=100k]
__global__ void p1d_scatter(const int* __restrict__ dst, const int* __restrict__ src,
                            const float* __restrict__ w, const int* __restrict__ blockCount,
                            const int* __restrict__ bstart, int2* __restrict__ temp,
                            int E, int B) {
    __shared__ int cur[256];
    int t = threadIdx.x;
    if (t < B) cur[t] = bstart[t] + blockCount[(long long)blockIdx.x * B + t];
    __syncthreads();
    int base = blockIdx.x * CHUNK;
    int end = min(base + CHUNK, E);
    for (int e = base + t; e < end; e += THREADS) {
        int d = dst[e];
        int b = d >> BKT_BITS;
        int pos = atomicAdd(&cur[b], 1);                       // LDS atomic w/ return
        temp[pos] = make_int2(src[e] | ((d & (BKT_NODES - 1)) << 17),
                              __float_as_int(w[e]));
    }
}

// ---- p2a: per-bucket histogram + weighted degree -> rowptr + norm (UNPADDED) ----
__global__ void p2a_norm(const int2* __restrict__ temp, const int* __restrict__ bstart,
                         int* __restrict__ rowptr, float* __restrict__ norm,
                         int N, int E, int B) {
    __shared__ int cnt[BKT_NODES];
    __shared__ float degs[BKT_NODES];
    __shared__ int sm[256];
    int b = blockIdx.x, t = threadIdx.x;
    int ebeg = bstart[b], eend = bstart[b + 1];
    for (int i = t; i < BKT_NODES; i += THREADS) { cnt[i] = 0; degs[i] = 0.0f; }
    __syncthreads();
    for (int e = ebeg + t; e < eend; e += THREADS) {
        int2 pk = temp[e];
        int dl = (pk.x >> 17) & (BKT_NODES - 1);
        atomicAdd(&cnt[dl], 1);
        atomicAdd(&degs[dl], __int_as_float(pk.y));
    }
    __syncthreads();
    // block exclusive scan of cnt[512]
    int run = 0;
    for (int base = 0; base < BKT_NODES; base += 256) {
        int v = cnt[base + t];
        sm[t] = v;
        __syncthreads();
        for (int off = 1; off < 256; off <<= 1) {
            int u = (t >= off) ? sm[t - off] : 0;
            __syncthreads();
            sm[t] += u;
            __syncthreads();
        }
        cnt[base + t] = run + sm[t] - v;    // reuse cnt as exclusive offsets
        run += sm[255];
        __syncthreads();
    }
    int node0 = b << BKT_BITS;
    for (int i = t; i < BKT_NODES; i += THREADS) {
        int node = node0 + i;
        if (node < N) {
            rowptr[node] = ebeg + cnt[i];
            norm[node] = rsqrtf(fmaxf(degs[i], 1.0f));
        }
    }
    if (b == 0 && t == 0) rowptr[N] = E;
}

// ---- p2b: placement with coef = w * norm[src] baked in ----
__global__ void p2b_place(const int2* __restrict__ temp, const int* __restrict__ bstart,
                          const int* __restrict__ rowptr, const float* __restrict__ norm,
                          int2* __restrict__ packed, int N, int E, int B) {
    __shared__ int cur[BKT_NODES];
    int b = blockIdx.x, t = threadIdx.x;
    int ebeg = bstart[b], eend = bstart[b + 1];
    int node0 = b << BKT_BITS;
    for (int i = t; i < BKT_NODES; i += THREADS) {
        int node = node0 + i;
        cur[i] = (node < N) ? rowptr[node] : E;
    }
    __syncthreads();
    for (int e = ebeg + t; e < eend; e += THREADS) {
        int2 pk = temp[e];
        int dl = (pk.x >> 17) & (BKT_NODES - 1);
        int s = pk.x & 0x1ffff;
        int pos = atomicAdd(&cur[dl], 1);                      // LDS atomic w/ return
        float c = __int_as_float(pk.y) * norm[s];
        packed[pos] = make_int2(s, __float_as_int(c));
    }
}

// ---- h (fp32) -> bf16 packed pairs, 4 elems/thread ----
__global__ void tobf16_kernel(const float* __restrict__ h, unsigned* __restrict__ hbf2,
                              long long nd4) {
    long long i = (long long)blockIdx.x * blockDim.x + threadIdx.x;
    if (i < nd4) {
        float4 v = ((const float4*)h)[i];
        ((uint2*)hbf2)[i] = make_uint2(f2bf(v.x) | (f2bf(v.y) << 16),
                                       f2bf(v.z) | (f2bf(v.w) << 16));
    }
}

// ---- gather layer 1: quarter-wave (16 lanes) per node, lane = 4 dims, unroll 4 ----
// EXACT r6 register shape (4 int2 meta + 4 uint2 rows + 16 accs = 32 VGPRs);
// coef pre-baked in packed[].y so no norm[src] load in the loop.
__global__ void gather1_kernel(const uint2* __restrict__ h_in, const int2* __restrict__ packed,
                               const int* __restrict__ rowptr, const float* __restrict__ norm,
                               uint2* __restrict__ h_out, int N) {
    int node = blockIdx.x * (blockDim.x >> 4) + (threadIdx.x >> 4);
    int lane = threadIdx.x & 15;
    if (node >= N) return;
    int j = rowptr[node], end = rowptr[node + 1];
    float a00 = 0, a01 = 0, a02 = 0, a03 = 0;
    float a10 = 0, a11 = 0, a12 = 0, a13 = 0;
    float a20 = 0, a21 = 0, a22 = 0, a23 = 0;
    float a30 = 0, a31 = 0, a32 = 0, a33 = 0;
    for (; j + 4 <= end; j += 4) {
        int2 p0 = packed[j], p1 = packed[j + 1], p2 = packed[j + 2], p3 = packed[j + 3];
        uint2 r0 = h_in[((long long)p0.x << 4) + lane];
        uint2 r1 = h_in[((long long)p1.x << 4) + lane];
        uint2 r2 = h_in[((long long)p2.x << 4) + lane];
        uint2 r3 = h_in[((long long)p3.x << 4) + lane];
        float c0 = __int_as_float(p0.y);
        float c1 = __int_as_float(p1.y);
        float c2 = __int_as_float(p2.y);
        float c3 = __int_as_float(p3.y);
        float2 f0a = bfpair(r0.x), f0b = bfpair(r0.y);
        float2 f1a = bfpair(r1.x), f1b = bfpair(r1.y);
        float2 f2a = bfpair(r2.x), f2b = bfpair(r2.y);
        float2 f3a = bfpair(r3.x), f3b = bfpair(r3.y);
        a00 = fmaf(f0a.x, c0, a00); a01 = fmaf(f0a.y, c0, a01);
        a02 = fmaf(f0b.x, c0, a02); a03 = fmaf(f0b.y, c0, a03);
        a10 = fmaf(f1a.x, c1, a10); a11 = fmaf(f1a.y, c1, a11);
        a12 = fmaf(f1b.x, c1, a12); a13 = fmaf(f1b.y, c1, a13);
        a20 = fmaf(f2a.x, c2, a20); a21 = fmaf(f2a.y, c2, a21);
        a22 = fmaf(f2b.x, c2, a22); a23 = fmaf(f2b.y, c2, a23);
        a30 = fmaf(f3a.x, c3, a30); a31 = fmaf(f3a.y, c3, a31);
        a32 = fmaf(f3b.x, c3, a32); a33 = fmaf(f3b.y, c3, a33);
    }
    for (; j < end; ++j) {
        int2 p = packed[j];
        uint2 r = h_in[((long long)p.x << 4) + lane];
        float c = __int_as_float(p.y);
        float2 fa = bfpair(r.x), fb = bfpair(r.y);
        a00 = fmaf(fa.x, c, a00); a01 = fmaf(fa.y, c, a01);
        a02 = fmaf(fb.x, c, a02); a03 = fmaf(fb.y, c, a03);
    }
    float nv = norm[node];
    float d0 = ((a00 + a10) + (a20 + a30)) * nv;
    float d1 = ((a01 + a11) + (a21 + a31)) * nv;
    float d2 = ((a02 + a12) + (a22 + a32)) * nv;
    float d3 = ((a03 + a13) + (a23 + a33)) * nv;
    h_out[((long long)node << 4) + lane] =
        make_uint2(f2bf(d0) | (f2bf(d1) << 16), f2bf(d2) | (f2bf(d3) << 16));
}

// ---- gather layer 2 + mean: out = (h0 + h1 + norm*sum h1[src]*coef)/3 ----
__global__ void gather2_final_kernel(const uint2* __restrict__ h0bf, const uint2* __restrict__ h1bf,
                                     const int2* __restrict__ packed, const int* __restrict__ rowptr,
                                     const float* __restrict__ norm, float* __restrict__ out, int N) {
    int node = blockIdx.x * (blockDim.x >> 4) + (threadIdx.x >> 4);
    int lane = threadIdx.x & 15;
    if (node >= N) return;
    int j = rowptr[node], end = rowptr[node + 1];
    float a00 = 0, a01 = 0, a02 = 0, a03 = 0;
    float a10 = 0, a11 = 0, a12 = 0, a13 = 0;
    float a20 = 0, a21 = 0, a22 = 0, a23 = 0;
    float a30 = 0, a31 = 0, a32 = 0, a33 = 0;
    for (; j + 4 <= end; j += 4) {
        int2 p0 = packed[j], p1 = packed[j + 1], p2 = packed[j + 2], p3 = packed[j + 3];
        uint2 r0 = h1bf[((long long)p0.x << 4) + lane];
        uint2 r1 = h1bf[((long long)p1.x << 4) + lane];
        uint2 r2 = h1bf[((long long)p2.x << 4) + lane];
        uint2 r3 = h1bf[((long long)p3.x << 4) + lane];
        float c0 = __int_as_float(p0.y);
        float c1 = __int_as_float(p1.y);
        float c2 = __int_as_float(p2.y);
        float c3 = __int_as_float(p3.y);
        float2 f0a = bfpair(r0.x), f0b = bfpair(r0.y);
        float2 f1a = bfpair(r1.x), f1b = bfpair(r1.y);
        float2 f2a = bfpair(r2.x), f2b = bfpair(r2.y);
        float2 f3a = bfpair(r3.x), f3b = bfpair(r3.y);
        a00 = fmaf(f0a.x, c0, a00); a01 = fmaf(f0a.y, c0, a01);
        a02 = fmaf(f0b.x, c0, a02); a03 = fmaf(f0b.y, c0, a03);
        a10 = fmaf(f1a.x, c1, a10); a11 = fmaf(f1a.y, c1, a11);
        a12 = fmaf(f1b.x, c1, a12); a13 = fmaf(f1b.y, c1, a13);
        a20 = fmaf(f2a.x, c2, a20); a21 = fmaf(f2a.y, c2, a21);
        a22 = fmaf(f2b.x, c2, a22); a23 = fmaf(f2b.y, c2, a23);
        a30 = fmaf(f3a.x, c3, a30); a31 = fmaf(f3a.y, c3, a31);
        a32 = fmaf(f3b.x, c3, a32); a33 = fmaf(f3b.y, c3, a33);
    }
    for (; j < end; ++j) {
        int2 p = packed[j];
        uint2 r = h1bf[((long long)p.x << 4) + lane];
        float c = __int_as_float(p.y);
        float2 fa = bfpair(r.x), fb = bfpair(r.y);
        a00 = fmaf(fa.x, c, a00); a01 = fmaf(fa.y, c, a01);
        a02 = fmaf(fb.x, c, a02); a03 = fmaf(fb.y, c, a03);
    }
    long long idx = ((long long)node << 4) + lane;
    float nv = norm[node];
    uint2 h0r = h0bf[idx], h1r = h1bf[idx];
    float2 h0a = bfpair(h0r.x), h0b = bfpair(h0r.y);
    float2 h1a = bfpair(h1r.x), h1b = bfpair(h1r.y);
    float4 o;
    o.x = (h0a.x + h1a.x + ((a00 + a10) + (a20 + a30)) * nv) * (1.0f / 3.0f);
    o.y = (h0a.y + h1a.y + ((a01 + a11) + (a21 + a31)) * nv) * (1.0f / 3.0f);
    o.z = (h0b.x + h1b.x + ((a02 + a12) + (a22 + a32)) * nv) * (1.0f / 3.0f);
    o.w = (h0b.y + h1b.y + ((a03 + a13) + (a23 + a33)) * nv) * (1.0f / 3.0f);
    ((float4*)out)[idx] = o;
}

extern "C" void kernel_launch(void* const* d_in, const int* in_sizes, int n_in,
                              void* d_out, int out_size, void* d_ws, size_t ws_size,
                              hipStream_t stream) {
    const float* h   = (const float*)d_in[0];
    const float* w   = (const float*)d_in[1];
    const int*   src = (const int*)d_in[2];
    const int*   dst = (const int*)d_in[3];
    const int N = in_sizes[0] / D;   // 100000
    const int E = in_sizes[1];       // 1600000
    float* out = (float*)d_out;

    const int B = (N + BKT_NODES - 1) >> BKT_BITS;   // 196
    const int NBLK = (E + CHUNK - 1) / CHUNK;        // 196

    // ---- workspace layout ----
    char* ws = (char*)d_ws;
    size_t off = 0;
    auto alloc = [&](size_t bytes, size_t align) -> char* {
        off = (off + align - 1) & ~(align - 1);
        char* p = ws + off;
        off += bytes;
        return p;
    };
    float* norm     = (float*)alloc((size_t)N * 4, 16);
    int*   rowptr   = (int*)  alloc((size_t)(N + 1) * 4, 16);
    int*   total    = (int*)  alloc((size_t)B * 4, 16);
    int*   bstart   = (int*)  alloc((size_t)(B + 1) * 4, 16);
    int*   blockCnt = (int*)  alloc((size_t)NBLK * B * 4, 16);
    int2*  packed   = (int2*) alloc((size_t)E * 8, 16);
    // temp (build phase) time-shares with h1bf (gather phase)
    char*  shared_region = alloc((size_t)E * 8, 128);
    int2*     temp = (int2*)shared_region;
    unsigned* h1bf = (unsigned*)shared_region;
    unsigned* h0bf = (unsigned*)alloc((size_t)N * D * 2, 128);

    const int nodes_per_block = THREADS / 16;        // quarter-wave per node
    const int gather_blocks = (N + nodes_per_block - 1) / nodes_per_block;
    const long long nd4 = (long long)N * D / 4;
    const int cvt_blocks = (int)((nd4 + THREADS - 1) / THREADS);

    // CSR build: zero global atomics (LDS counting sort), coef baked in p2b
    p1a_hist<<<NBLK, THREADS, 0, stream>>>(dst, blockCnt, E, B);
    p1b_scanblocks<<<B, 256, 0, stream>>>(blockCnt, total, NBLK, B);
    p1c_scanbuckets<<<1, 256, 0, stream>>>(total, bstart, B, E);
    p1d_scatter<<<NBLK, THREADS, 0, stream>>>(dst, src, w, blockCnt, bstart, temp, E, B);
    p2a_norm<<<B, 256, 0, stream>>>(temp, bstart, rowptr, norm, N, E, B);
    p2b_place<<<B, 256, 0, stream>>>(temp, bstart, rowptr, norm, packed, N, E, B);

    // h -> bf16
    tobf16_kernel<<<cvt_blocks, THREADS, 0, stream>>>(h, h0bf, nd4);

    // gathers (r6-proven register shape: 4-deep MLP, 32 VGPRs)
    gather1_kernel<<<gather_blocks, THREADS, 0, stream>>>((const uint2*)h0bf, packed, rowptr,
                                                          norm, (uint2*)h1bf, N);
    gather2_final_kernel<<<gather_blocks, THREADS, 0, stream>>>((const uint2*)h0bf, (const uint2*)h1bf,
                                                                packed, rowptr, norm, out, N);
}